// Round 7
// baseline (673.083 us; speedup 1.0000x reference)
//
#include <hip/hip_runtime.h>
#include <stdint.h>

// ---------------------------------------------------------------------------
// GCN 3-layer forward:  out = A_hat @ relu(A_hat @ relu(A_hat @ x W0 + b0) W1 + b1) W2 + b2
// A_hat = D^-1/2 (A + I) D^-1/2:
//   out[c] = dinv[c] * sum_{edges r->c} dinv[r]*h[r] + dinv[c]^2 * h[c] + b
//
// R2: agg FETCH == 8 XCD x sizeof(H) (random graph) -> H stored bf16.
// R3: one-shot scatter was 64B-partial-line bound -> bucketed 2-pass sort.
// R4: feature-sliced gather: 16-feat slab (3.2 MB) per XCD L2, slice =
//   blockIdx&7. FETCH 195->60 MB. Edge entry 4 B (src 17b | deg 15b).
// R5: LDS rsqrt LUT for edge weights (VALU 64->52%).
// R6: dur flat at 95us -> latency/L2-thrash bound, not VALU. (a) nontemporal
//   epk loads + output stores so streams don't evict the pinned H slab
//   (FETCH 60.8 vs 36 ideal = slab re-fetch); (b) unroll 4->8 for 2x MLP.
// ---------------------------------------------------------------------------

static inline size_t ws_align(size_t x) { return (x + 255) & ~(size_t)255; }

#define SRCM 0x1FFFFu  // n <= 131072

typedef float __f2 __attribute__((ext_vector_type(2)));

__device__ __forceinline__ int eidx(const void* p, size_t i, int is64) {
  return is64 ? (int)((const long long*)p)[i] : ((const int*)p)[i];
}

__device__ __forceinline__ uint16_t f2bf(float f) {  // RNE float->bf16
  uint32_t u = __float_as_uint(f);
  u += 0x7fffu + ((u >> 16) & 1u);
  return (uint16_t)(u >> 16);
}
__device__ __forceinline__ float bf_lo(uint32_t h) { return __uint_as_float(h << 16); }
__device__ __forceinline__ float bf_hi(uint32_t h) { return __uint_as_float(h & 0xffff0000u); }

// Detect int64 vs int32 edge_index (little-endian: int64 high words are 0).
__global__ void detect_k(const int* ei, int* flag) {
  if (threadIdx.x == 0 && blockIdx.x == 0) {
    int allz = 1;
    for (int i = 1; i < 128; i += 2)
      if (ei[i] != 0) { allz = 0; break; }
    *flag = allz;
  }
}

// --- passA: bucket histogram via per-block LDS counters --------------------
__global__ __launch_bounds__(256) void passA_k(const void* ei, const int* __restrict__ flag,
                                               int* __restrict__ bucket_cnt, int E, int NB) {
  __shared__ int cnt[256];
  int t = threadIdx.x;
  cnt[t] = 0;
  __syncthreads();
  int is64 = *flag;
  for (int e = blockIdx.x * 256 + t; e < E; e += gridDim.x * 256) {
    int c = eidx(ei, (size_t)E + e, is64);
    atomicAdd(&cnt[c >> 9], 1);
  }
  __syncthreads();
  if (t < NB && cnt[t]) atomicAdd(&bucket_cnt[t], cnt[t]);
}

// --- bscan: exclusive scan of bucket_cnt -> bucket_offs; init gcursor ------
__global__ __launch_bounds__(256) void bscan_k(const int* __restrict__ bucket_cnt,
                                               int* __restrict__ bucket_offs,
                                               int* __restrict__ gcursor, int NB) {
  __shared__ int sh[256];
  int t = threadIdx.x;
  int v = (t < NB) ? bucket_cnt[t] : 0;
  sh[t] = v;
  __syncthreads();
  for (int off = 1; off < 256; off <<= 1) {
    int x = (t >= off) ? sh[t - off] : 0;
    __syncthreads();
    sh[t] += x;
    __syncthreads();
  }
  if (t < NB) {
    int excl = sh[t] - v;
    bucket_offs[t] = excl;
    gcursor[t] = excl;
  }
  if (t == NB - 1) bucket_offs[NB] = sh[t];
}

// --- passB: partition edges into bucket-contiguous epk_binned --------------
__global__ __launch_bounds__(256) void passB_k(const void* ei, const int* __restrict__ flag,
                                               int* __restrict__ gcursor,
                                               int2* __restrict__ epk_binned, int E, int NB) {
  __shared__ int2 sorted[4096];                       // 32 KB
  __shared__ int cnt[256], bbase[256], gb[256], cur[256];
  const int t = threadIdx.x;
  const int base = blockIdx.x * 4096;
  const int CH = min(4096, E - base);
  const int is64 = *flag;

  cnt[t] = 0;
  __syncthreads();
  for (int i = t; i < CH; i += 256) {
    int c = eidx(ei, (size_t)E + base + i, is64);
    atomicAdd(&cnt[c >> 9], 1);
  }
  __syncthreads();
  {
    int v = cnt[t];
    __shared__ int sh[256];
    sh[t] = v;
    __syncthreads();
    for (int off = 1; off < 256; off <<= 1) {
      int x = (t >= off) ? sh[t - off] : 0;
      __syncthreads();
      sh[t] += x;
      __syncthreads();
    }
    bbase[t] = sh[t] - v;
    gb[t] = (t < NB && v) ? atomicAdd(&gcursor[t], v) : 0;
    cur[t] = 0;
  }
  __syncthreads();
  for (int i = t; i < CH; i += 256) {
    int r = eidx(ei, (size_t)base + i, is64);
    int c = eidx(ei, (size_t)E + base + i, is64);
    int b = c >> 9;
    int rank = atomicAdd(&cur[b], 1);
    sorted[bbase[b] + rank] = make_int2(r, c);
  }
  __syncthreads();
  for (int i = t; i < CH; i += 256) {
    int2 v = sorted[i];
    int b = v.y >> 9;
    epk_binned[gb[b] + (i - bbase[b])] = v;
  }
}

// --- passC0: per-bucket degree count -> deg[] and offs[] (coalesced) -------
__global__ __launch_bounds__(256) void passC0_k(const int2* __restrict__ epk_binned,
                                                const int* __restrict__ bucket_offs,
                                                int* __restrict__ deg, int* __restrict__ offs,
                                                int n, int NB) {
  __shared__ int dcnt[512];
  __shared__ int s[256];
  const int t = threadIdx.x;
  const int b = blockIdx.x;
  dcnt[t] = 0; dcnt[t + 256] = 0;
  __syncthreads();
  const int lo = bucket_offs[b], hi = bucket_offs[b + 1];
  for (int i = lo + t; i < hi; i += 256)
    atomicAdd(&dcnt[epk_binned[i].y & 511], 1);
  __syncthreads();
  int d0 = dcnt[2 * t], d1 = dcnt[2 * t + 1];
  int pv = d0 + d1;
  s[t] = pv;
  __syncthreads();
  for (int off = 1; off < 256; off <<= 1) {
    int x = (t >= off) ? s[t - off] : 0;
    __syncthreads();
    s[t] += x;
    __syncthreads();
  }
  int pex = s[t] - pv;
  const int node0 = b << 9;
  int g0 = node0 + 2 * t, g1 = node0 + 2 * t + 1;
  if (g0 < n) { deg[g0] = d0; offs[g0] = lo + pex; }
  if (g1 < n) { deg[g1] = d1; offs[g1] = lo + pex + d0; }
  if (b == NB - 1 && t == 0) offs[n] = hi;
}

// --- passC: final placement by exact dest; pack (src | min(deg,511)<<17) ---
__global__ __launch_bounds__(256) void passC_k(const int2* __restrict__ epk_binned,
                                               const int* __restrict__ bucket_offs,
                                               const int* __restrict__ offs,
                                               const int* __restrict__ deg,
                                               uint32_t* __restrict__ epk) {
  __shared__ int cur[512];
  const int t = threadIdx.x;
  const int b = blockIdx.x;
  cur[t] = 0; cur[t + 256] = 0;
  __syncthreads();
  const int lo = bucket_offs[b], hi = bucket_offs[b + 1];
  for (int i = lo + t; i < hi; i += 256) {
    int2 v = epk_binned[i];
    int pos = offs[v.y] + atomicAdd(&cur[v.y & 511], 1);
    int dv = min(deg[v.x], 511);   // LUT range; Poisson(16) max ~45, 10-sigma safe
    epk[pos] = (uint32_t)v.x | ((uint32_t)dv << 17);
  }
}

// --- LDS-tiled SGEMM: Hs (sliced bf16) = X @ W ------------------------------
template <int COLS, bool SLICED_IN>
__global__ __launch_bounds__(256) void gemm_k(const float* __restrict__ X,
                                              const float* __restrict__ W,
                                              uint16_t* __restrict__ H, int N) {
  constexpr int KB = 32;
  constexpr int CG = COLS / 8;
  constexpr int RG = 256 / CG;
  constexpr int ROWS = RG * 8;
  constexpr int XP = ROWS + 4;

  __shared__ float Xs[KB][XP];
  __shared__ float Ws[KB][COLS];

  const int tid = threadIdx.x;
  const int cg = tid % CG, rg = tid / CG;
  const int c0 = cg * 8, rr0 = rg * 8;
  const int rowbase = blockIdx.x * ROWS;
  const float4* X4 = (const float4*)X;

  float acc[8][8];
#pragma unroll
  for (int a = 0; a < 8; ++a)
#pragma unroll
    for (int b = 0; b < 8; ++b) acc[a][b] = 0.f;

  for (int k0 = 0; k0 < 128; k0 += KB) {
    __syncthreads();
#pragma unroll
    for (int i = tid; i < KB * (COLS / 4); i += 256) {
      int kk = i / (COLS / 4);
      int cc = i % (COLS / 4);
      float4 w = ((const float4*)(W + (size_t)(k0 + kk) * COLS))[cc];
      ((float4*)&Ws[kk][0])[cc] = w;
    }
#pragma unroll
    for (int i = tid; i < ROWS * (KB / 4); i += 256) {
      int rr = i / (KB / 4);
      int k4 = i % (KB / 4);
      int gr = rowbase + rr;
      if (gr >= N) gr = N - 1;
      float4 xv;
      if (SLICED_IN) {
        int k = k0 + k4 * 4;
        int s = k >> 4, q = (k & 15) >> 2;
        xv = X4[((size_t)s * N + gr) * 4 + q];
      } else {
        xv = X4[(size_t)gr * 32 + (k0 >> 2) + k4];
      }
      Xs[k4 * 4 + 0][rr] = xv.x;
      Xs[k4 * 4 + 1][rr] = xv.y;
      Xs[k4 * 4 + 2][rr] = xv.z;
      Xs[k4 * 4 + 3][rr] = xv.w;
    }
    __syncthreads();
#pragma unroll 2
    for (int k = 0; k < KB; ++k) {
      float4 xa = *(const float4*)&Xs[k][rr0];
      float4 xb = *(const float4*)&Xs[k][rr0 + 4];
      float4 wa = *(const float4*)&Ws[k][c0];
      float4 wb = *(const float4*)&Ws[k][c0 + 4];
      float xr[8] = {xa.x, xa.y, xa.z, xa.w, xb.x, xb.y, xb.z, xb.w};
      float wr[8] = {wa.x, wa.y, wa.z, wa.w, wb.x, wb.y, wb.z, wb.w};
#pragma unroll
      for (int a = 0; a < 8; ++a)
#pragma unroll
        for (int b = 0; b < 8; ++b) acc[a][b] = fmaf(xr[a], wr[b], acc[a][b]);
    }
  }
  uint32_t* HW = (uint32_t*)H;
  const int wbase = c0 >> 1;
  const int sl = wbase >> 3;
  const int woff = wbase & 7;
#pragma unroll
  for (int a = 0; a < 8; ++a) {
    int row = rowbase + rr0 + a;
    if (row < N) {
      uint32_t p[4];
#pragma unroll
      for (int q = 0; q < 4; ++q)
        p[q] = (uint32_t)f2bf(acc[a][2 * q]) | ((uint32_t)f2bf(acc[a][2 * q + 1]) << 16);
      uint4 ov = make_uint4(p[0], p[1], p[2], p[3]);
      *(uint4*)&HW[((size_t)sl * N + row) * 8 + woff] = ov;
    }
  }
}

// --- Sliced aggregate, 128 feats: 8 slices x 16 feats. slice = blockIdx&7 --
// Subgroup of 8 lanes per dest; LDS rsqrt LUT; NT epk loads + NT output
// stores (streams must not evict the pinned H slab); 8-deep unrolled gather.
__global__ __launch_bounds__(256) void agg128s_k(const uint32_t* __restrict__ HW,
                                                 const int* __restrict__ offs,
                                                 const uint32_t* __restrict__ epk,
                                                 const float* __restrict__ bias,
                                                 float* __restrict__ Aout,
                                                 int relu, int N) {
  __shared__ float lut[512];
  {
    int t = threadIdx.x;
    lut[t] = rsqrtf((float)t + 1.f);
    lut[t + 256] = rsqrtf((float)t + 257.f);
  }
  __syncthreads();
  const int s = blockIdx.x & 7;
  const int g = blockIdx.x >> 3;
  const int lane = threadIdx.x & 63;
  const int wid = threadIdx.x >> 6;
  const int d = lane >> 3, w = lane & 7;
  const int c = g * 32 + wid * 8 + d;
  if (c >= N) return;
  const uint32_t* Hs = HW + (size_t)s * N * 8;
  int e0 = offs[c], e1 = offs[c + 1];
  float ax = 0.f, ay = 0.f;
  int e = e0;
  for (; e + 8 <= e1; e += 8) {
    uint32_t p0 = __builtin_nontemporal_load(epk + e);
    uint32_t p1 = __builtin_nontemporal_load(epk + e + 1);
    uint32_t p2 = __builtin_nontemporal_load(epk + e + 2);
    uint32_t p3 = __builtin_nontemporal_load(epk + e + 3);
    uint32_t p4 = __builtin_nontemporal_load(epk + e + 4);
    uint32_t p5 = __builtin_nontemporal_load(epk + e + 5);
    uint32_t p6 = __builtin_nontemporal_load(epk + e + 6);
    uint32_t p7 = __builtin_nontemporal_load(epk + e + 7);
    uint32_t h0 = Hs[(size_t)(p0 & SRCM) * 8 + w];
    uint32_t h1 = Hs[(size_t)(p1 & SRCM) * 8 + w];
    uint32_t h2 = Hs[(size_t)(p2 & SRCM) * 8 + w];
    uint32_t h3 = Hs[(size_t)(p3 & SRCM) * 8 + w];
    uint32_t h4 = Hs[(size_t)(p4 & SRCM) * 8 + w];
    uint32_t h5 = Hs[(size_t)(p5 & SRCM) * 8 + w];
    uint32_t h6 = Hs[(size_t)(p6 & SRCM) * 8 + w];
    uint32_t h7 = Hs[(size_t)(p7 & SRCM) * 8 + w];
    float w0 = lut[p0 >> 17], w1 = lut[p1 >> 17], w2 = lut[p2 >> 17], w3 = lut[p3 >> 17];
    float w4 = lut[p4 >> 17], w5 = lut[p5 >> 17], w6 = lut[p6 >> 17], w7 = lut[p7 >> 17];
    ax = fmaf(w0, bf_lo(h0), ax); ay = fmaf(w0, bf_hi(h0), ay);
    ax = fmaf(w1, bf_lo(h1), ax); ay = fmaf(w1, bf_hi(h1), ay);
    ax = fmaf(w2, bf_lo(h2), ax); ay = fmaf(w2, bf_hi(h2), ay);
    ax = fmaf(w3, bf_lo(h3), ax); ay = fmaf(w3, bf_hi(h3), ay);
    ax = fmaf(w4, bf_lo(h4), ax); ay = fmaf(w4, bf_hi(h4), ay);
    ax = fmaf(w5, bf_lo(h5), ax); ay = fmaf(w5, bf_hi(h5), ay);
    ax = fmaf(w6, bf_lo(h6), ax); ay = fmaf(w6, bf_hi(h6), ay);
    ax = fmaf(w7, bf_lo(h7), ax); ay = fmaf(w7, bf_hi(h7), ay);
  }
  for (; e + 4 <= e1; e += 4) {
    uint32_t p0 = __builtin_nontemporal_load(epk + e);
    uint32_t p1 = __builtin_nontemporal_load(epk + e + 1);
    uint32_t p2 = __builtin_nontemporal_load(epk + e + 2);
    uint32_t p3 = __builtin_nontemporal_load(epk + e + 3);
    uint32_t h0 = Hs[(size_t)(p0 & SRCM) * 8 + w];
    uint32_t h1 = Hs[(size_t)(p1 & SRCM) * 8 + w];
    uint32_t h2 = Hs[(size_t)(p2 & SRCM) * 8 + w];
    uint32_t h3 = Hs[(size_t)(p3 & SRCM) * 8 + w];
    float w0 = lut[p0 >> 17], w1 = lut[p1 >> 17], w2 = lut[p2 >> 17], w3 = lut[p3 >> 17];
    ax = fmaf(w0, bf_lo(h0), ax); ay = fmaf(w0, bf_hi(h0), ay);
    ax = fmaf(w1, bf_lo(h1), ax); ay = fmaf(w1, bf_hi(h1), ay);
    ax = fmaf(w2, bf_lo(h2), ax); ay = fmaf(w2, bf_hi(h2), ay);
    ax = fmaf(w3, bf_lo(h3), ax); ay = fmaf(w3, bf_hi(h3), ay);
  }
  for (; e < e1; ++e) {
    uint32_t p = __builtin_nontemporal_load(epk + e);
    uint32_t h = Hs[(size_t)(p & SRCM) * 8 + w];
    float wt = lut[p >> 17];
    ax = fmaf(wt, bf_lo(h), ax); ay = fmaf(wt, bf_hi(h), ay);
  }
  float dc = lut[min(e1 - e0, 511)];
  uint32_t hc = Hs[(size_t)c * 8 + w];
  float rx = fmaf(dc, ax, dc * dc * bf_lo(hc)) + bias[s * 16 + 2 * w];
  float ry = fmaf(dc, ay, dc * dc * bf_hi(hc)) + bias[s * 16 + 2 * w + 1];
  if (relu) { rx = fmaxf(rx, 0.f); ry = fmaxf(ry, 0.f); }
  __f2 res; res.x = rx; res.y = ry;
  __builtin_nontemporal_store(res, (__f2*)(Aout + ((size_t)s * N + c) * 16) + w);
}

// --- Sliced aggregate, 64 feats: 4 slices on XCD pairs; dense fp32 out -----
__global__ __launch_bounds__(256) void agg64s_k(const uint32_t* __restrict__ HW,
                                                const int* __restrict__ offs,
                                                const uint32_t* __restrict__ epk,
                                                const float* __restrict__ bias,
                                                float* __restrict__ out, int N) {
  __shared__ float lut[512];
  {
    int t = threadIdx.x;
    lut[t] = rsqrtf((float)t + 1.f);
    lut[t + 256] = rsqrtf((float)t + 257.f);
  }
  __syncthreads();
  const int r = blockIdx.x & 7;
  const int s = r >> 1;          // slice 0..3
  const int half = r & 1;
  const int ng = (N + 31) >> 5;
  const int nh = (ng + 1) >> 1;
  const int g = half * nh + (blockIdx.x >> 3);
  if (g >= ng) return;
  const int lane = threadIdx.x & 63;
  const int wid = threadIdx.x >> 6;
  const int d = lane >> 3, w = lane & 7;
  const int c = g * 32 + wid * 8 + d;
  if (c >= N) return;
  const uint32_t* Hs = HW + (size_t)s * N * 8;
  int e0 = offs[c], e1 = offs[c + 1];
  float ax = 0.f, ay = 0.f;
  int e = e0;
  for (; e + 8 <= e1; e += 8) {
    uint32_t p0 = __builtin_nontemporal_load(epk + e);
    uint32_t p1 = __builtin_nontemporal_load(epk + e + 1);
    uint32_t p2 = __builtin_nontemporal_load(epk + e + 2);
    uint32_t p3 = __builtin_nontemporal_load(epk + e + 3);
    uint32_t p4 = __builtin_nontemporal_load(epk + e + 4);
    uint32_t p5 = __builtin_nontemporal_load(epk + e + 5);
    uint32_t p6 = __builtin_nontemporal_load(epk + e + 6);
    uint32_t p7 = __builtin_nontemporal_load(epk + e + 7);
    uint32_t h0 = Hs[(size_t)(p0 & SRCM) * 8 + w];
    uint32_t h1 = Hs[(size_t)(p1 & SRCM) * 8 + w];
    uint32_t h2 = Hs[(size_t)(p2 & SRCM) * 8 + w];
    uint32_t h3 = Hs[(size_t)(p3 & SRCM) * 8 + w];
    uint32_t h4 = Hs[(size_t)(p4 & SRCM) * 8 + w];
    uint32_t h5 = Hs[(size_t)(p5 & SRCM) * 8 + w];
    uint32_t h6 = Hs[(size_t)(p6 & SRCM) * 8 + w];
    uint32_t h7 = Hs[(size_t)(p7 & SRCM) * 8 + w];
    float w0 = lut[p0 >> 17], w1 = lut[p1 >> 17], w2 = lut[p2 >> 17], w3 = lut[p3 >> 17];
    float w4 = lut[p4 >> 17], w5 = lut[p5 >> 17], w6 = lut[p6 >> 17], w7 = lut[p7 >> 17];
    ax = fmaf(w0, bf_lo(h0), ax); ay = fmaf(w0, bf_hi(h0), ay);
    ax = fmaf(w1, bf_lo(h1), ax); ay = fmaf(w1, bf_hi(h1), ay);
    ax = fmaf(w2, bf_lo(h2), ax); ay = fmaf(w2, bf_hi(h2), ay);
    ax = fmaf(w3, bf_lo(h3), ax); ay = fmaf(w3, bf_hi(h3), ay);
    ax = fmaf(w4, bf_lo(h4), ax); ay = fmaf(w4, bf_hi(h4), ay);
    ax = fmaf(w5, bf_lo(h5), ax); ay = fmaf(w5, bf_hi(h5), ay);
    ax = fmaf(w6, bf_lo(h6), ax); ay = fmaf(w6, bf_hi(h6), ay);
    ax = fmaf(w7, bf_lo(h7), ax); ay = fmaf(w7, bf_hi(h7), ay);
  }
  for (; e + 4 <= e1; e += 4) {
    uint32_t p0 = __builtin_nontemporal_load(epk + e);
    uint32_t p1 = __builtin_nontemporal_load(epk + e + 1);
    uint32_t p2 = __builtin_nontemporal_load(epk + e + 2);
    uint32_t p3 = __builtin_nontemporal_load(epk + e + 3);
    uint32_t h0 = Hs[(size_t)(p0 & SRCM) * 8 + w];
    uint32_t h1 = Hs[(size_t)(p1 & SRCM) * 8 + w];
    uint32_t h2 = Hs[(size_t)(p2 & SRCM) * 8 + w];
    uint32_t h3 = Hs[(size_t)(p3 & SRCM) * 8 + w];
    float w0 = lut[p0 >> 17], w1 = lut[p1 >> 17], w2 = lut[p2 >> 17], w3 = lut[p3 >> 17];
    ax = fmaf(w0, bf_lo(h0), ax); ay = fmaf(w0, bf_hi(h0), ay);
    ax = fmaf(w1, bf_lo(h1), ax); ay = fmaf(w1, bf_hi(h1), ay);
    ax = fmaf(w2, bf_lo(h2), ax); ay = fmaf(w2, bf_hi(h2), ay);
    ax = fmaf(w3, bf_lo(h3), ax); ay = fmaf(w3, bf_hi(h3), ay);
  }
  for (; e < e1; ++e) {
    uint32_t p = __builtin_nontemporal_load(epk + e);
    uint32_t h = Hs[(size_t)(p & SRCM) * 8 + w];
    float wt = lut[p >> 17];
    ax = fmaf(wt, bf_lo(h), ax); ay = fmaf(wt, bf_hi(h), ay);
  }
  float dc = lut[min(e1 - e0, 511)];
  uint32_t hc = Hs[(size_t)c * 8 + w];
  float rx = fmaf(dc, ax, dc * dc * bf_lo(hc)) + bias[s * 16 + 2 * w];
  float ry = fmaf(dc, ay, dc * dc * bf_hi(hc)) + bias[s * 16 + 2 * w + 1];
  __f2 res; res.x = rx; res.y = ry;
  __builtin_nontemporal_store(res, (__f2*)(out + (size_t)c * 64) + s * 8 + w);
}

extern "C" void kernel_launch(void* const* d_in, const int* in_sizes, int n_in,
                              void* d_out, int out_size, void* d_ws, size_t ws_size,
                              hipStream_t stream) {
  const float* x  = (const float*)d_in[0];
  const void*  ei = d_in[1];
  const float* W0 = (const float*)d_in[2];
  const float* b0 = (const float*)d_in[3];
  const float* W1 = (const float*)d_in[4];
  const float* b1 = (const float*)d_in[5];
  const float* W2 = (const float*)d_in[6];
  const float* b2 = (const float*)d_in[7];
  float* out = (float*)d_out;

  const int n = in_sizes[0] / 128;   // 100000
  const int E = in_sizes[1] / 2;     // 1600000
  const int NB = (n + 511) >> 9;     // buckets of 512 dests (NB <= 256)

  char* ws = (char*)d_ws;
  size_t off = 0;
  auto alloc = [&](size_t bytes) { char* p = ws + off; off = ws_align(off + bytes); return p; };
  int*      bucket_cnt  = (int*)alloc(256 * 4);
  int*      bucket_offs = (int*)alloc(257 * 4);
  int*      gcursor     = (int*)alloc(256 * 4);
  int*      deg         = (int*)alloc((size_t)n * 4);
  int*      offs        = (int*)alloc((size_t)(n + 1) * 4);
  int*      flag        = (int*)alloc(4);
  int2*     epk_binned  = (int2*)alloc((size_t)E * 8);
  uint32_t* epk         = (uint32_t*)alloc((size_t)E * 4);
  uint16_t* hbuf        = (uint16_t*)alloc((size_t)n * 128 * 2);  // sliced bf16 H
  float*    abuf        = (float*)alloc((size_t)n * 128 * 4);     // sliced fp32 acts
  (void)ws_size;

  hipMemsetAsync(bucket_cnt, 0, 256 * 4, stream);

  detect_k<<<1, 64, 0, stream>>>((const int*)ei, flag);
  passA_k<<<512, 256, 0, stream>>>(ei, flag, bucket_cnt, E, NB);
  bscan_k<<<1, 256, 0, stream>>>(bucket_cnt, bucket_offs, gcursor, NB);
  passB_k<<<(E + 4095) / 4096, 256, 0, stream>>>(ei, flag, gcursor, epk_binned, E, NB);
  passC0_k<<<NB, 256, 0, stream>>>(epk_binned, bucket_offs, deg, offs, n, NB);
  passC_k<<<NB, 256, 0, stream>>>(epk_binned, bucket_offs, offs, deg, epk);

  const int agg128_blocks = 8 * ((n + 31) / 32);
  const int ng = (n + 31) >> 5, nh = (ng + 1) >> 1;
  const int agg64_blocks = 8 * nh;

  // Layer 0 (dense x input)
  gemm_k<128, false><<<(n + 127) / 128, 256, 0, stream>>>(x, W0, hbuf, n);
  agg128s_k<<<agg128_blocks, 256, 0, stream>>>((const uint32_t*)hbuf, offs, epk, b0, abuf, 1, n);
  // Layer 1 (sliced activations)
  gemm_k<128, true><<<(n + 127) / 128, 256, 0, stream>>>(abuf, W1, hbuf, n);
  agg128s_k<<<agg128_blocks, 256, 0, stream>>>((const uint32_t*)hbuf, offs, epk, b1, abuf, 1, n);
  // Layer 2 (no relu) -> d_out dense fp32
  gemm_k<64, true><<<(n + 255) / 256, 256, 0, stream>>>(abuf, W2, hbuf, n);
  agg64s_k<<<agg64_blocks, 256, 0, stream>>>((const uint32_t*)hbuf, offs, epk, b2, out, n);
}

// Round 8
// 524.382 us; speedup vs baseline: 1.2836x; 1.2836x over previous
//
#include <hip/hip_runtime.h>
#include <stdint.h>

// ---------------------------------------------------------------------------
// GCN 3-layer forward:  out = A_hat @ relu(A_hat @ relu(A_hat @ x W0 + b0) W1 + b1) W2 + b2
// A_hat = D^-1/2 (A + I) D^-1/2. With pre-scaled rows h'[r] = dinv[r]*h[r]:
//   out[c] = dinv[c] * ( sum_{edges r->c} h'[r] + h'[c] ) + b
//
// R2: agg FETCH == 8 XCD x sizeof(H) (random graph) -> H stored bf16.
// R3: one-shot scatter was 64B-partial-line bound -> bucketed 2-pass sort.
// R4: feature-sliced gather: 16-feat slab (3.2 MB) per XCD L2, slice =
//   blockIdx&7. FETCH 195->60 MB.
// R5: LDS rsqrt LUT (VALU 64->52%), dur flat -> latency-bound.
// R6/R7: NT loads on epk REGRESSED (FETCH +11MB, dur 95->143): epk lines are
//   re-read across unroll blocks; nt evicts them. NT stores kept (write-once).
// R8: revert NT loads; pre-scale H by dinv at GEMM output -> epk is plain src,
//   no LUT, per-edge work = 1 broadcast load + 1 gather + 2 unpack + 2 add.
// ---------------------------------------------------------------------------

static inline size_t ws_align(size_t x) { return (x + 255) & ~(size_t)255; }

#define SRCM 0x1FFFFu  // n <= 131072

typedef float __f2 __attribute__((ext_vector_type(2)));

__device__ __forceinline__ int eidx(const void* p, size_t i, int is64) {
  return is64 ? (int)((const long long*)p)[i] : ((const int*)p)[i];
}

__device__ __forceinline__ uint16_t f2bf(float f) {  // RNE float->bf16
  uint32_t u = __float_as_uint(f);
  u += 0x7fffu + ((u >> 16) & 1u);
  return (uint16_t)(u >> 16);
}
__device__ __forceinline__ float bf_lo(uint32_t h) { return __uint_as_float(h << 16); }
__device__ __forceinline__ float bf_hi(uint32_t h) { return __uint_as_float(h & 0xffff0000u); }

// Detect int64 vs int32 edge_index (little-endian: int64 high words are 0).
__global__ void detect_k(const int* ei, int* flag) {
  if (threadIdx.x == 0 && blockIdx.x == 0) {
    int allz = 1;
    for (int i = 1; i < 128; i += 2)
      if (ei[i] != 0) { allz = 0; break; }
    *flag = allz;
  }
}

// --- passA: bucket histogram via per-block LDS counters --------------------
__global__ __launch_bounds__(256) void passA_k(const void* ei, const int* __restrict__ flag,
                                               int* __restrict__ bucket_cnt, int E, int NB) {
  __shared__ int cnt[256];
  int t = threadIdx.x;
  cnt[t] = 0;
  __syncthreads();
  int is64 = *flag;
  for (int e = blockIdx.x * 256 + t; e < E; e += gridDim.x * 256) {
    int c = eidx(ei, (size_t)E + e, is64);
    atomicAdd(&cnt[c >> 9], 1);
  }
  __syncthreads();
  if (t < NB && cnt[t]) atomicAdd(&bucket_cnt[t], cnt[t]);
}

// --- bscan: exclusive scan of bucket_cnt -> bucket_offs; init gcursor ------
__global__ __launch_bounds__(256) void bscan_k(const int* __restrict__ bucket_cnt,
                                               int* __restrict__ bucket_offs,
                                               int* __restrict__ gcursor, int NB) {
  __shared__ int sh[256];
  int t = threadIdx.x;
  int v = (t < NB) ? bucket_cnt[t] : 0;
  sh[t] = v;
  __syncthreads();
  for (int off = 1; off < 256; off <<= 1) {
    int x = (t >= off) ? sh[t - off] : 0;
    __syncthreads();
    sh[t] += x;
    __syncthreads();
  }
  if (t < NB) {
    int excl = sh[t] - v;
    bucket_offs[t] = excl;
    gcursor[t] = excl;
  }
  if (t == NB - 1) bucket_offs[NB] = sh[t];
}

// --- passB: partition edges into bucket-contiguous epk_binned --------------
__global__ __launch_bounds__(256) void passB_k(const void* ei, const int* __restrict__ flag,
                                               int* __restrict__ gcursor,
                                               int2* __restrict__ epk_binned, int E, int NB) {
  __shared__ int2 sorted[4096];                       // 32 KB
  __shared__ int cnt[256], bbase[256], gb[256], cur[256];
  const int t = threadIdx.x;
  const int base = blockIdx.x * 4096;
  const int CH = min(4096, E - base);
  const int is64 = *flag;

  cnt[t] = 0;
  __syncthreads();
  for (int i = t; i < CH; i += 256) {
    int c = eidx(ei, (size_t)E + base + i, is64);
    atomicAdd(&cnt[c >> 9], 1);
  }
  __syncthreads();
  {
    int v = cnt[t];
    __shared__ int sh[256];
    sh[t] = v;
    __syncthreads();
    for (int off = 1; off < 256; off <<= 1) {
      int x = (t >= off) ? sh[t - off] : 0;
      __syncthreads();
      sh[t] += x;
      __syncthreads();
    }
    bbase[t] = sh[t] - v;
    gb[t] = (t < NB && v) ? atomicAdd(&gcursor[t], v) : 0;
    cur[t] = 0;
  }
  __syncthreads();
  for (int i = t; i < CH; i += 256) {
    int r = eidx(ei, (size_t)base + i, is64);
    int c = eidx(ei, (size_t)E + base + i, is64);
    int b = c >> 9;
    int rank = atomicAdd(&cur[b], 1);
    sorted[bbase[b] + rank] = make_int2(r, c);
  }
  __syncthreads();
  for (int i = t; i < CH; i += 256) {
    int2 v = sorted[i];
    int b = v.y >> 9;
    epk_binned[gb[b] + (i - bbase[b])] = v;
  }
}

// --- passC0: per-bucket degree count -> deg[] and offs[] (coalesced) -------
__global__ __launch_bounds__(256) void passC0_k(const int2* __restrict__ epk_binned,
                                                const int* __restrict__ bucket_offs,
                                                int* __restrict__ deg, int* __restrict__ offs,
                                                int n, int NB) {
  __shared__ int dcnt[512];
  __shared__ int s[256];
  const int t = threadIdx.x;
  const int b = blockIdx.x;
  dcnt[t] = 0; dcnt[t + 256] = 0;
  __syncthreads();
  const int lo = bucket_offs[b], hi = bucket_offs[b + 1];
  for (int i = lo + t; i < hi; i += 256)
    atomicAdd(&dcnt[epk_binned[i].y & 511], 1);
  __syncthreads();
  int d0 = dcnt[2 * t], d1 = dcnt[2 * t + 1];
  int pv = d0 + d1;
  s[t] = pv;
  __syncthreads();
  for (int off = 1; off < 256; off <<= 1) {
    int x = (t >= off) ? s[t - off] : 0;
    __syncthreads();
    s[t] += x;
    __syncthreads();
  }
  int pex = s[t] - pv;
  const int node0 = b << 9;
  int g0 = node0 + 2 * t, g1 = node0 + 2 * t + 1;
  if (g0 < n) { deg[g0] = d0; offs[g0] = lo + pex; }
  if (g1 < n) { deg[g1] = d1; offs[g1] = lo + pex + d0; }
  if (b == NB - 1 && t == 0) offs[n] = hi;
}

__global__ void dinv_k(const int* __restrict__ deg, float* __restrict__ dinv, int n) {
  int i = blockIdx.x * blockDim.x + threadIdx.x;
  if (i < n) dinv[i] = rsqrtf((float)deg[i] + 1.0f);  // +1 = self loop
}

// --- passC: final placement by exact dest; entry = plain src ---------------
__global__ __launch_bounds__(256) void passC_k(const int2* __restrict__ epk_binned,
                                               const int* __restrict__ bucket_offs,
                                               const int* __restrict__ offs,
                                               uint32_t* __restrict__ epk) {
  __shared__ int cur[512];
  const int t = threadIdx.x;
  const int b = blockIdx.x;
  cur[t] = 0; cur[t + 256] = 0;
  __syncthreads();
  const int lo = bucket_offs[b], hi = bucket_offs[b + 1];
  for (int i = lo + t; i < hi; i += 256) {
    int2 v = epk_binned[i];
    int pos = offs[v.y] + atomicAdd(&cur[v.y & 511], 1);
    epk[pos] = (uint32_t)v.x;
  }
}

// --- LDS-tiled SGEMM: Hs (sliced bf16) = dinv[row] * (X @ W) ---------------
// X read dense (layer 0) or sliced fp32 (layers 1/2). Output rows pre-scaled
// by dinv so agg needs no per-edge weight.
template <int COLS, bool SLICED_IN>
__global__ __launch_bounds__(256) void gemm_k(const float* __restrict__ X,
                                              const float* __restrict__ W,
                                              const float* __restrict__ dinv,
                                              uint16_t* __restrict__ H, int N) {
  constexpr int KB = 32;
  constexpr int CG = COLS / 8;
  constexpr int RG = 256 / CG;
  constexpr int ROWS = RG * 8;
  constexpr int XP = ROWS + 4;

  __shared__ float Xs[KB][XP];
  __shared__ float Ws[KB][COLS];

  const int tid = threadIdx.x;
  const int cg = tid % CG, rg = tid / CG;
  const int c0 = cg * 8, rr0 = rg * 8;
  const int rowbase = blockIdx.x * ROWS;
  const float4* X4 = (const float4*)X;

  float acc[8][8];
#pragma unroll
  for (int a = 0; a < 8; ++a)
#pragma unroll
    for (int b = 0; b < 8; ++b) acc[a][b] = 0.f;

  for (int k0 = 0; k0 < 128; k0 += KB) {
    __syncthreads();
#pragma unroll
    for (int i = tid; i < KB * (COLS / 4); i += 256) {
      int kk = i / (COLS / 4);
      int cc = i % (COLS / 4);
      float4 w = ((const float4*)(W + (size_t)(k0 + kk) * COLS))[cc];
      ((float4*)&Ws[kk][0])[cc] = w;
    }
#pragma unroll
    for (int i = tid; i < ROWS * (KB / 4); i += 256) {
      int rr = i / (KB / 4);
      int k4 = i % (KB / 4);
      int gr = rowbase + rr;
      if (gr >= N) gr = N - 1;
      float4 xv;
      if (SLICED_IN) {
        int k = k0 + k4 * 4;
        int s = k >> 4, q = (k & 15) >> 2;
        xv = X4[((size_t)s * N + gr) * 4 + q];
      } else {
        xv = X4[(size_t)gr * 32 + (k0 >> 2) + k4];
      }
      Xs[k4 * 4 + 0][rr] = xv.x;
      Xs[k4 * 4 + 1][rr] = xv.y;
      Xs[k4 * 4 + 2][rr] = xv.z;
      Xs[k4 * 4 + 3][rr] = xv.w;
    }
    __syncthreads();
#pragma unroll 2
    for (int k = 0; k < KB; ++k) {
      float4 xa = *(const float4*)&Xs[k][rr0];
      float4 xb = *(const float4*)&Xs[k][rr0 + 4];
      float4 wa = *(const float4*)&Ws[k][c0];
      float4 wb = *(const float4*)&Ws[k][c0 + 4];
      float xr[8] = {xa.x, xa.y, xa.z, xa.w, xb.x, xb.y, xb.z, xb.w};
      float wr[8] = {wa.x, wa.y, wa.z, wa.w, wb.x, wb.y, wb.z, wb.w};
#pragma unroll
      for (int a = 0; a < 8; ++a)
#pragma unroll
        for (int b = 0; b < 8; ++b) acc[a][b] = fmaf(xr[a], wr[b], acc[a][b]);
    }
  }
  uint32_t* HW = (uint32_t*)H;
  const int wbase = c0 >> 1;
  const int sl = wbase >> 3;
  const int woff = wbase & 7;
#pragma unroll
  for (int a = 0; a < 8; ++a) {
    int row = rowbase + rr0 + a;
    if (row < N) {
      float sc = dinv[row];
      uint32_t p[4];
#pragma unroll
      for (int q = 0; q < 4; ++q)
        p[q] = (uint32_t)f2bf(sc * acc[a][2 * q]) | ((uint32_t)f2bf(sc * acc[a][2 * q + 1]) << 16);
      uint4 ov = make_uint4(p[0], p[1], p[2], p[3]);
      *(uint4*)&HW[((size_t)sl * N + row) * 8 + woff] = ov;
    }
  }
}

// --- Sliced aggregate, 128 feats: 8 slices x 16 feats. slice = blockIdx&7 --
// Subgroup of 8 lanes per dest. H pre-scaled -> per edge: broadcast epk load,
// gather h', unpack, add. NT only on output stores (write-once stream).
__global__ __launch_bounds__(256) void agg128s_k(const uint32_t* __restrict__ HW,
                                                 const int* __restrict__ offs,
                                                 const uint32_t* __restrict__ epk,
                                                 const float* __restrict__ bias,
                                                 float* __restrict__ Aout,
                                                 int relu, int N) {
  const int s = blockIdx.x & 7;
  const int g = blockIdx.x >> 3;
  const int lane = threadIdx.x & 63;
  const int wid = threadIdx.x >> 6;
  const int d = lane >> 3, w = lane & 7;
  const int c = g * 32 + wid * 8 + d;
  if (c >= N) return;
  const uint32_t* Hs = HW + (size_t)s * N * 8;
  int e0 = offs[c], e1 = offs[c + 1];
  float ax = 0.f, ay = 0.f;
  int e = e0;
  for (; e + 8 <= e1; e += 8) {
    uint32_t p0 = epk[e],     p1 = epk[e + 1], p2 = epk[e + 2], p3 = epk[e + 3];
    uint32_t p4 = epk[e + 4], p5 = epk[e + 5], p6 = epk[e + 6], p7 = epk[e + 7];
    uint32_t h0 = Hs[(size_t)p0 * 8 + w];
    uint32_t h1 = Hs[(size_t)p1 * 8 + w];
    uint32_t h2 = Hs[(size_t)p2 * 8 + w];
    uint32_t h3 = Hs[(size_t)p3 * 8 + w];
    uint32_t h4 = Hs[(size_t)p4 * 8 + w];
    uint32_t h5 = Hs[(size_t)p5 * 8 + w];
    uint32_t h6 = Hs[(size_t)p6 * 8 + w];
    uint32_t h7 = Hs[(size_t)p7 * 8 + w];
    ax += bf_lo(h0); ay += bf_hi(h0);
    ax += bf_lo(h1); ay += bf_hi(h1);
    ax += bf_lo(h2); ay += bf_hi(h2);
    ax += bf_lo(h3); ay += bf_hi(h3);
    ax += bf_lo(h4); ay += bf_hi(h4);
    ax += bf_lo(h5); ay += bf_hi(h5);
    ax += bf_lo(h6); ay += bf_hi(h6);
    ax += bf_lo(h7); ay += bf_hi(h7);
  }
  for (; e + 4 <= e1; e += 4) {
    uint32_t p0 = epk[e], p1 = epk[e + 1], p2 = epk[e + 2], p3 = epk[e + 3];
    uint32_t h0 = Hs[(size_t)p0 * 8 + w];
    uint32_t h1 = Hs[(size_t)p1 * 8 + w];
    uint32_t h2 = Hs[(size_t)p2 * 8 + w];
    uint32_t h3 = Hs[(size_t)p3 * 8 + w];
    ax += bf_lo(h0); ay += bf_hi(h0);
    ax += bf_lo(h1); ay += bf_hi(h1);
    ax += bf_lo(h2); ay += bf_hi(h2);
    ax += bf_lo(h3); ay += bf_hi(h3);
  }
  for (; e < e1; ++e) {
    uint32_t h = Hs[(size_t)epk[e] * 8 + w];
    ax += bf_lo(h); ay += bf_hi(h);
  }
  float dc = rsqrtf((float)(e1 - e0) + 1.f);
  uint32_t hc = Hs[(size_t)c * 8 + w];
  float rx = fmaf(dc, ax + bf_lo(hc), bias[s * 16 + 2 * w]);
  float ry = fmaf(dc, ay + bf_hi(hc), bias[s * 16 + 2 * w + 1]);
  if (relu) { rx = fmaxf(rx, 0.f); ry = fmaxf(ry, 0.f); }
  __f2 res; res.x = rx; res.y = ry;
  __builtin_nontemporal_store(res, (__f2*)(Aout + ((size_t)s * N + c) * 16) + w);
}

// --- Sliced aggregate, 64 feats: 4 slices on XCD pairs; dense fp32 out -----
__global__ __launch_bounds__(256) void agg64s_k(const uint32_t* __restrict__ HW,
                                                const int* __restrict__ offs,
                                                const uint32_t* __restrict__ epk,
                                                const float* __restrict__ bias,
                                                float* __restrict__ out, int N) {
  const int r = blockIdx.x & 7;
  const int s = r >> 1;          // slice 0..3
  const int half = r & 1;
  const int ng = (N + 31) >> 5;
  const int nh = (ng + 1) >> 1;
  const int g = half * nh + (blockIdx.x >> 3);
  if (g >= ng) return;
  const int lane = threadIdx.x & 63;
  const int wid = threadIdx.x >> 6;
  const int d = lane >> 3, w = lane & 7;
  const int c = g * 32 + wid * 8 + d;
  if (c >= N) return;
  const uint32_t* Hs = HW + (size_t)s * N * 8;
  int e0 = offs[c], e1 = offs[c + 1];
  float ax = 0.f, ay = 0.f;
  int e = e0;
  for (; e + 8 <= e1; e += 8) {
    uint32_t p0 = epk[e],     p1 = epk[e + 1], p2 = epk[e + 2], p3 = epk[e + 3];
    uint32_t p4 = epk[e + 4], p5 = epk[e + 5], p6 = epk[e + 6], p7 = epk[e + 7];
    uint32_t h0 = Hs[(size_t)p0 * 8 + w];
    uint32_t h1 = Hs[(size_t)p1 * 8 + w];
    uint32_t h2 = Hs[(size_t)p2 * 8 + w];
    uint32_t h3 = Hs[(size_t)p3 * 8 + w];
    uint32_t h4 = Hs[(size_t)p4 * 8 + w];
    uint32_t h5 = Hs[(size_t)p5 * 8 + w];
    uint32_t h6 = Hs[(size_t)p6 * 8 + w];
    uint32_t h7 = Hs[(size_t)p7 * 8 + w];
    ax += bf_lo(h0); ay += bf_hi(h0);
    ax += bf_lo(h1); ay += bf_hi(h1);
    ax += bf_lo(h2); ay += bf_hi(h2);
    ax += bf_lo(h3); ay += bf_hi(h3);
    ax += bf_lo(h4); ay += bf_hi(h4);
    ax += bf_lo(h5); ay += bf_hi(h5);
    ax += bf_lo(h6); ay += bf_hi(h6);
    ax += bf_lo(h7); ay += bf_hi(h7);
  }
  for (; e + 4 <= e1; e += 4) {
    uint32_t p0 = epk[e], p1 = epk[e + 1], p2 = epk[e + 2], p3 = epk[e + 3];
    uint32_t h0 = Hs[(size_t)p0 * 8 + w];
    uint32_t h1 = Hs[(size_t)p1 * 8 + w];
    uint32_t h2 = Hs[(size_t)p2 * 8 + w];
    uint32_t h3 = Hs[(size_t)p3 * 8 + w];
    ax += bf_lo(h0); ay += bf_hi(h0);
    ax += bf_lo(h1); ay += bf_hi(h1);
    ax += bf_lo(h2); ay += bf_hi(h2);
    ax += bf_lo(h3); ay += bf_hi(h3);
  }
  for (; e < e1; ++e) {
    uint32_t h = Hs[(size_t)epk[e] * 8 + w];
    ax += bf_lo(h); ay += bf_hi(h);
  }
  float dc = rsqrtf((float)(e1 - e0) + 1.f);
  uint32_t hc = Hs[(size_t)c * 8 + w];
  float rx = fmaf(dc, ax + bf_lo(hc), bias[s * 16 + 2 * w]);
  float ry = fmaf(dc, ay + bf_hi(hc), bias[s * 16 + 2 * w + 1]);
  __f2 res; res.x = rx; res.y = ry;
  __builtin_nontemporal_store(res, (__f2*)(out + (size_t)c * 64) + s * 8 + w);
}

extern "C" void kernel_launch(void* const* d_in, const int* in_sizes, int n_in,
                              void* d_out, int out_size, void* d_ws, size_t ws_size,
                              hipStream_t stream) {
  const float* x  = (const float*)d_in[0];
  const void*  ei = d_in[1];
  const float* W0 = (const float*)d_in[2];
  const float* b0 = (const float*)d_in[3];
  const float* W1 = (const float*)d_in[4];
  const float* b1 = (const float*)d_in[5];
  const float* W2 = (const float*)d_in[6];
  const float* b2 = (const float*)d_in[7];
  float* out = (float*)d_out;

  const int n = in_sizes[0] / 128;   // 100000
  const int E = in_sizes[1] / 2;     // 1600000
  const int NB = (n + 511) >> 9;     // buckets of 512 dests (NB <= 256)

  char* ws = (char*)d_ws;
  size_t off = 0;
  auto alloc = [&](size_t bytes) { char* p = ws + off; off = ws_align(off + bytes); return p; };
  int*      bucket_cnt  = (int*)alloc(256 * 4);
  int*      bucket_offs = (int*)alloc(257 * 4);
  int*      gcursor     = (int*)alloc(256 * 4);
  int*      deg         = (int*)alloc((size_t)n * 4);
  int*      offs        = (int*)alloc((size_t)(n + 1) * 4);
  float*    dinv        = (float*)alloc((size_t)n * 4);
  int*      flag        = (int*)alloc(4);
  int2*     epk_binned  = (int2*)alloc((size_t)E * 8);
  uint32_t* epk         = (uint32_t*)alloc((size_t)E * 4);
  uint16_t* hbuf        = (uint16_t*)alloc((size_t)n * 128 * 2);  // sliced bf16 H'
  float*    abuf        = (float*)alloc((size_t)n * 128 * 4);     // sliced fp32 acts
  (void)ws_size;

  hipMemsetAsync(bucket_cnt, 0, 256 * 4, stream);

  detect_k<<<1, 64, 0, stream>>>((const int*)ei, flag);
  passA_k<<<512, 256, 0, stream>>>(ei, flag, bucket_cnt, E, NB);
  bscan_k<<<1, 256, 0, stream>>>(bucket_cnt, bucket_offs, gcursor, NB);
  passB_k<<<(E + 4095) / 4096, 256, 0, stream>>>(ei, flag, gcursor, epk_binned, E, NB);
  passC0_k<<<NB, 256, 0, stream>>>(epk_binned, bucket_offs, deg, offs, n, NB);
  dinv_k<<<(n + 255) / 256, 256, 0, stream>>>(deg, dinv, n);
  passC_k<<<NB, 256, 0, stream>>>(epk_binned, bucket_offs, offs, epk);

  const int agg128_blocks = 8 * ((n + 31) / 32);
  const int ng = (n + 31) >> 5, nh = (ng + 1) >> 1;
  const int agg64_blocks = 8 * nh;

  // Layer 0 (dense x input)
  gemm_k<128, false><<<(n + 127) / 128, 256, 0, stream>>>(x, W0, dinv, hbuf, n);
  agg128s_k<<<agg128_blocks, 256, 0, stream>>>((const uint32_t*)hbuf, offs, epk, b0, abuf, 1, n);
  // Layer 1 (sliced activations)
  gemm_k<128, true><<<(n + 127) / 128, 256, 0, stream>>>(abuf, W1, dinv, hbuf, n);
  agg128s_k<<<agg128_blocks, 256, 0, stream>>>((const uint32_t*)hbuf, offs, epk, b1, abuf, 1, n);
  // Layer 2 (no relu) -> d_out dense fp32
  gemm_k<64, true><<<(n + 255) / 256, 256, 0, stream>>>(abuf, W2, dinv, hbuf, n);
  agg64s_k<<<agg64_blocks, 256, 0, stream>>>((const uint32_t*)hbuf, offs, epk, b2, out, n);
}